// Round 9
// baseline (655.304 us; speedup 1.0000x reference)
//
#include <hip/hip_runtime.h>

#define NNODES 50000
#define NEDGES 800000
#define NTOT   (NEDGES + NNODES)   // edges + self loops
#define F_IN   50
#define KPAD1  64                  // F_IN padded to 64
#define HEADS  4
#define C1     64
#define HC1    256                 // HEADS*C1
#define NC     121
#define K1S    320                 // layer1 GEMM K: 256 (agg) + 64 (x0)
#define K3S    1280                // layer3 GEMM K: 1024 (agg) + 256 (x2)
#define N2S    512                 // layer2 GEMM N: 256 (W2) + 256 (res2)

typedef unsigned short ushort_t;
typedef __attribute__((ext_vector_type(4))) unsigned short ushort4_t;
typedef __attribute__((ext_vector_type(8))) unsigned short ushort8;
typedef __attribute__((ext_vector_type(8))) __bf16 bf16x8;
typedef __attribute__((ext_vector_type(4))) float f32x4;

__device__ __forceinline__ ushort_t f2bf(float f) {
    union { float f; unsigned int u; } v; v.f = f;
    unsigned int u = v.u;
    return (ushort_t)((u + 0x7fffu + ((u >> 16) & 1u)) >> 16);   // RNE
}
__device__ __forceinline__ float bf2f(ushort_t s) {
    union { unsigned int u; float f; } v; v.u = ((unsigned int)s) << 16;
    return v.f;
}
// 4 consecutive bf16 -> f32x4 (2 shl + 2 and; feeds v_pk_fma_f32 consumers)
__device__ __forceinline__ f32x4 bf4_to_f32x4(ushort4_t v) {
    union { ushort4_t u4; unsigned int d[2]; } u; u.u4 = v;
    union { unsigned int u; float f; } c0, c1, c2, c3;
    c0.u = u.d[0] << 16; c1.u = u.d[0] & 0xffff0000u;
    c2.u = u.d[1] << 16; c3.u = u.d[1] & 0xffff0000u;
    f32x4 r; r.x = c0.f; r.y = c1.f; r.z = c2.f; r.w = c3.f;
    return r;
}
__device__ __forceinline__ float lrelu(float x) { return x > 0.f ? x : 0.2f * x; }

// ---------------------------------------------------------------- CSR build
__global__ void count_kernel(const int* __restrict__ ei, int* __restrict__ cnt) {
    int i = blockIdx.x * blockDim.x + threadIdx.x;
    if (i >= NTOT) return;
    int d = (i < NEDGES) ? ei[NEDGES + i] : (i - NEDGES);
    if ((unsigned)d >= NNODES) d = 0;
    atomicAdd(&cnt[d], 1);
}

#define SCB 256
__global__ __launch_bounds__(SCB)
void scan1_kernel(const int* __restrict__ cnt, int* __restrict__ incl,
                  int* __restrict__ bsums, int n) {
    __shared__ int buf[SCB];
    int b = blockIdx.x, tid = threadIdx.x;
    int i = b * SCB + tid;
    int v = (i < n) ? cnt[i] : 0;
    buf[tid] = v;
    __syncthreads();
    for (int off = 1; off < SCB; off <<= 1) {
        int t = (tid >= off) ? buf[tid - off] : 0;
        __syncthreads();
        buf[tid] += t;
        __syncthreads();
    }
    if (i < n) incl[i] = buf[tid];
    if (tid == SCB - 1) bsums[b] = buf[tid];
}

__global__ __launch_bounds__(SCB)
void scan2_kernel(int* __restrict__ bsums, int nb) {
    __shared__ int buf[SCB];
    int tid = threadIdx.x;
    int v = (tid < nb) ? bsums[tid] : 0;
    buf[tid] = v;
    __syncthreads();
    for (int off = 1; off < SCB; off <<= 1) {
        int t = (tid >= off) ? buf[tid - off] : 0;
        __syncthreads();
        buf[tid] += t;
        __syncthreads();
    }
    if (tid < nb) bsums[tid] = buf[tid] - v;   // exclusive
}

__global__ __launch_bounds__(SCB)
void scan3_kernel(const int* __restrict__ cnt, const int* __restrict__ incl,
                  const int* __restrict__ bsums, int* __restrict__ row_ptr,
                  int* __restrict__ cursor, int n) {
    int b = blockIdx.x, tid = threadIdx.x;
    int i = b * SCB + tid;
    if (i >= n) return;
    int e = bsums[b] + incl[i] - cnt[i];
    row_ptr[i] = e; cursor[i] = e;
    if (i == n - 1) row_ptr[n] = NTOT;
}

__global__ void scatter_kernel(const int* __restrict__ ei, int* __restrict__ cursor,
                               int* __restrict__ csr_src) {
    int i = blockIdx.x * blockDim.x + threadIdx.x;
    if (i >= NTOT) return;
    int s, d;
    if (i < NEDGES) { s = ei[i]; d = ei[NEDGES + i]; }
    else            { s = d = i - NEDGES; }
    if ((unsigned)d >= NNODES) d = 0;
    if ((unsigned)s >= NNODES) s = 0;
    int pos = atomicAdd(&cursor[d], 1);
    csr_src[pos] = s;
}

// ---------------------------------------------------------------- merged prep kernel
#define SZ_A (NNODES * KPAD1)     // x0b
#define SZ_B (HC1 * K1S)          // Bt1
#define SZ_C (N2S * HC1)          // Bt2
#define SZ_D (N2S)                // bias512
#define SZ_E (NC * K3S)           // Bt3
#define SZ_F (KPAD1 * 4)          // w_as1 / w_ad1
#define SZ_G (HC1 * 4)            // w_as2 / w_ad2 / w_as3 / w_ad3
#define PREP_TOTAL (SZ_A + SZ_B + SZ_C + SZ_D + SZ_E + 2 * SZ_F + 4 * SZ_G)

__global__ __launch_bounds__(256)
void prep_kernel(const float* __restrict__ x0,
                 const float* __restrict__ W1, const float* __restrict__ res1,
                 const float* __restrict__ W2, const float* __restrict__ res2,
                 const float* __restrict__ W3, const float* __restrict__ res3,
                 const float* __restrict__ as1, const float* __restrict__ ad1,
                 const float* __restrict__ as2, const float* __restrict__ ad2,
                 const float* __restrict__ as3, const float* __restrict__ ad3,
                 const float* __restrict__ b2,
                 ushort_t* __restrict__ x0b, ushort_t* __restrict__ Bt1,
                 ushort_t* __restrict__ Bt2, ushort_t* __restrict__ Bt3,
                 float* __restrict__ bias512,
                 float* __restrict__ w_as1, float* __restrict__ w_ad1,
                 float* __restrict__ w_as2, float* __restrict__ w_ad2,
                 float* __restrict__ w_as3, float* __restrict__ w_ad3) {
    int i = blockIdx.x * 256 + threadIdx.x;
    if (i < SZ_A) {
        int m = i >> 6, k = i & 63;
        x0b[i] = (k < F_IN) ? f2bf(x0[(size_t)m * F_IN + k]) : (ushort_t)0;
        return;
    }
    i -= SZ_A;
    if (i < SZ_B) {
        int c = i / K1S, kk = i - c * K1S;
        float v = 0.f;
        if (kk < 256) {
            int h = kk >> 6, k = kk & 63;
            if (k < F_IN && (c >> 6) == h) v = W1[(size_t)k * HC1 + c];
        } else {
            int k = kk - 256;
            if (k < F_IN) v = res1[(size_t)k * HC1 + c];
        }
        Bt1[i] = f2bf(v);
        return;
    }
    i -= SZ_B;
    if (i < SZ_C) {
        int c = i / HC1, k = i - c * HC1;
        float v = (c < HC1) ? W2[(size_t)k * HC1 + c] : res2[(size_t)k * HC1 + (c - HC1)];
        Bt2[i] = f2bf(v);
        return;
    }
    i -= SZ_C;
    if (i < SZ_D) {
        bias512[i] = (i < HC1) ? 0.f : b2[i - HC1];
        return;
    }
    i -= SZ_D;
    if (i < SZ_E) {
        int c = i / K3S, kk = i - c * K3S;
        float v;
        if (kk < 1024) {
            int h = kk >> 8, k = kk & 255;
            v = 0.25f * W3[(size_t)k * (HEADS * NC) + h * NC + c];
        } else {
            int k = kk - 1024;
            v = res3[(size_t)k * NC + c];
        }
        Bt3[i] = f2bf(v);
        return;
    }
    i -= SZ_E;
    if (i < 2 * SZ_F) {
        const float* a = (i < SZ_F) ? as1 : ad1;
        float* w = (i < SZ_F) ? w_as1 : w_ad1;
        int ii = (i < SZ_F) ? i : i - SZ_F;
        int k = ii >> 2, h = ii & 3;
        float s = 0.f;
        if (k < F_IN)
            for (int c = 0; c < C1; ++c) s += W1[(size_t)k * HC1 + h * C1 + c] * a[h * C1 + c];
        w[ii] = s;
        return;
    }
    i -= 2 * SZ_F;
    {
        int grp = i / SZ_G, ii = i - grp * SZ_G;
        int k = ii >> 2, h = ii & 3;
        float s = 0.f;
        if (grp < 2) {
            const float* a = grp ? ad2 : as2;
            for (int c = 0; c < C1; ++c) s += W2[(size_t)k * HC1 + h * C1 + c] * a[h * C1 + c];
            (grp ? w_ad2 : w_as2)[ii] = s;
        } else {
            const float* a = (grp == 3) ? ad3 : as3;
            for (int c = 0; c < NC; ++c) s += W3[(size_t)k * (HEADS * NC) + h * NC + c] * a[h * NC + c];
            ((grp == 3) ? w_ad3 : w_as3)[ii] = s;
        }
    }
}

// ---------------------------------------------------------------- MFMA GEMM (split-A)
#define BM 128
#define BN 128
#define BK 64
#define LDP (BK + 8)

__global__ __launch_bounds__(256)
void gemm_mfma_kernel(const ushort_t* __restrict__ A1, int lda1,
                      const ushort_t* __restrict__ A2, int lda2, int Ksplit,
                      const ushort_t* __restrict__ Bt, const float* __restrict__ bias,
                      float* __restrict__ Cf, ushort_t* __restrict__ Cb,
                      int M, int N, int K, int relu) {
    __shared__ ushort_t As[BM * LDP];
    __shared__ ushort_t Bs[BN * LDP];
    int tid = threadIdx.x;
    int lane = tid & 63;
    int wid = tid >> 6;
    int wm = (wid & 1) * 64, wn = (wid >> 1) * 64;
    int l15 = lane & 15;
    int q8 = (lane >> 4) * 8;
    int m0 = blockIdx.y * BM, n0 = blockIdx.x * BN;

    f32x4 acc[4][4] = {};

    for (int k0 = 0; k0 < K; k0 += BK) {
        #pragma unroll
        for (int it = 0; it < 4; ++it) {
            int c = tid + it * 256;
            int row = c >> 3, c8 = c & 7;
            int k = k0 + c8 * 8;
            ushort8 va = (ushort8)0;
            int gm = m0 + row;
            if (gm < M) {
                if (k < Ksplit) va = *(const ushort8*)&A1[(size_t)gm * lda1 + k];
                else            va = *(const ushort8*)&A2[(size_t)gm * lda2 + (k - Ksplit)];
            }
            *(ushort8*)&As[row * LDP + c8 * 8] = va;
            ushort8 vb = (ushort8)0;
            int gn = n0 + row;
            if (gn < N) vb = *(const ushort8*)&Bt[(size_t)gn * K + k];
            *(ushort8*)&Bs[row * LDP + c8 * 8] = vb;
        }
        __syncthreads();
        #pragma unroll
        for (int kk = 0; kk < BK; kk += 32) {
            bf16x8 af[4], bfr[4];
            #pragma unroll
            for (int mi = 0; mi < 4; ++mi)
                af[mi] = *(const bf16x8*)&As[(wm + mi * 16 + l15) * LDP + kk + q8];
            #pragma unroll
            for (int ni = 0; ni < 4; ++ni)
                bfr[ni] = *(const bf16x8*)&Bs[(wn + ni * 16 + l15) * LDP + kk + q8];
            #pragma unroll
            for (int mi = 0; mi < 4; ++mi)
                #pragma unroll
                for (int ni = 0; ni < 4; ++ni)
                    acc[mi][ni] = __builtin_amdgcn_mfma_f32_16x16x32_bf16(
                        af[mi], bfr[ni], acc[mi][ni], 0, 0, 0);
        }
        __syncthreads();
    }

    #pragma unroll
    for (int mi = 0; mi < 4; ++mi) {
        int mbase = m0 + wm + mi * 16 + (lane >> 4) * 4;
        #pragma unroll
        for (int ni = 0; ni < 4; ++ni) {
            int ncol = n0 + wn + ni * 16 + l15;
            if (ncol >= N) continue;
            float bv = bias ? bias[ncol] : 0.f;
            #pragma unroll
            for (int r = 0; r < 4; ++r) {
                int m = mbase + r;
                if (m >= M) continue;
                float v = acc[mi][ni][r] + bv;
                if (relu) v = fmaxf(v, 0.f);
                if (Cf) Cf[(size_t)m * N + ncol] = v;
                else    Cb[(size_t)m * N + ncol] = f2bf(v);
            }
        }
    }
}

// ---------------------------------------------------------------- logits GEMV
__global__ __launch_bounds__(64)
void logits_gemv_kernel(const ushort_t* __restrict__ X, int K,
                        const float* __restrict__ w_as, const float* __restrict__ w_ad,
                        float* __restrict__ als, float* __restrict__ ald) {
    int n = blockIdx.x, lane = threadIdx.x;
    float ps[HEADS] = {}, pd[HEADS] = {};
    for (int k0 = lane * 4; k0 < K; k0 += 256) {
        ushort4_t xv = *(const ushort4_t*)&X[(size_t)n * K + k0];
        float x[4] = {bf2f(xv.x), bf2f(xv.y), bf2f(xv.z), bf2f(xv.w)};
        #pragma unroll
        for (int j = 0; j < 4; ++j) {
            #pragma unroll
            for (int h = 0; h < HEADS; ++h) {
                ps[h] += x[j] * w_as[(k0 + j) * 4 + h];
                pd[h] += x[j] * w_ad[(k0 + j) * 4 + h];
            }
        }
    }
    #pragma unroll
    for (int off = 32; off; off >>= 1)
        #pragma unroll
        for (int h = 0; h < HEADS; ++h) {
            ps[h] += __shfl_xor(ps[h], off);
            pd[h] += __shfl_xor(pd[h], off);
        }
    if (lane == 0)
        #pragma unroll
        for (int h = 0; h < HEADS; ++h) {
            als[n * HEADS + h] = ps[h];
            ald[n * HEADS + h] = pd[h];
        }
}

// ---------------------------------------------------------------- softmax helpers (per-dst, 1 wave)
#define MAX_PASS(als_, ald_)                                                  \
    int beg = row_ptr[d], end = row_ptr[d + 1];                               \
    f32x4 aldd = *(const f32x4*)&(ald_)[d * 4];                               \
    float mx[HEADS] = {-1e30f, -1e30f, -1e30f, -1e30f};                       \
    for (int i = beg + lane; i < end; i += 64) {                              \
        f32x4 av = *(const f32x4*)&(als_)[csr_src[i] * 4];                    \
        _Pragma("unroll")                                                     \
        for (int h = 0; h < HEADS; ++h)                                       \
            mx[h] = fmaxf(mx[h], lrelu(av[h] + aldd[h]));                     \
    }                                                                         \
    _Pragma("unroll")                                                         \
    for (int off = 32; off; off >>= 1)                                        \
        _Pragma("unroll")                                                     \
        for (int h = 0; h < HEADS; ++h)                                       \
            mx[h] = fmaxf(mx[h], __shfl_xor(mx[h], off));

#define E_CHUNK(als_)                                                         \
    int i = base + lane;                                                      \
    int nv = end - base; if (nv > 64) nv = 64;                                \
    if (i < end) {                                                            \
        int s = csr_src[i];                                                   \
        ssrc[lane] = s;                                                       \
        f32x4 av = *(const f32x4*)&(als_)[s * 4];                             \
        f32x4 e;                                                              \
        _Pragma("unroll")                                                     \
        for (int h = 0; h < HEADS; ++h) {                                     \
            e[h] = __expf(lrelu(av[h] + aldd[h]) - mx[h]);                    \
            den[h] += e[h];                                                   \
        }                                                                     \
        *(f32x4*)&se[lane * 4] = e;                                           \
    }                                                                         \
    __syncthreads();

#define DEN_REDUCE                                                            \
    _Pragma("unroll")                                                         \
    for (int off = 32; off; off >>= 1)                                        \
        _Pragma("unroll")                                                     \
        for (int h = 0; h < HEADS; ++h)                                       \
            den[h] += __shfl_xor(den[h], off);                                \
    float rd[HEADS];                                                          \
    _Pragma("unroll")                                                         \
    for (int h = 0; h < HEADS; ++h) rd[h] = 1.f / den[h];

// ---------------------------------------------------------------- agg layer 1 (gather x0b 64 cols -> aggx1[N,256])
__global__ __launch_bounds__(64)
void agg1_kernel(const ushort_t* __restrict__ x0b,
                 const float* __restrict__ als, const float* __restrict__ ald,
                 const int* __restrict__ row_ptr, const int* __restrict__ csr_src,
                 ushort_t* __restrict__ aggx) {
    __shared__ int   ssrc[64];
    __shared__ float se[64 * 4];
    int d = blockIdx.x, lane = threadIdx.x;
    MAX_PASS(als, ald)
    float den[HEADS] = {};
    f32x4 acc = (f32x4)0.f;                   // acc[h] over heads (pk_fma)
    for (int base = beg; base < end; base += 64) {
        E_CHUNK(als)
        int j = 0;
        for (; j + 4 <= nv; j += 4) {
            int s0 = ssrc[j], s1 = ssrc[j + 1], s2 = ssrc[j + 2], s3 = ssrc[j + 3];
            f32x4 e0 = *(const f32x4*)&se[j * 4];
            f32x4 e1 = *(const f32x4*)&se[(j + 1) * 4];
            f32x4 e2 = *(const f32x4*)&se[(j + 2) * 4];
            f32x4 e3 = *(const f32x4*)&se[(j + 3) * 4];
            float x0v = bf2f(x0b[(size_t)s0 * KPAD1 + lane]);
            float x1v = bf2f(x0b[(size_t)s1 * KPAD1 + lane]);
            float x2v = bf2f(x0b[(size_t)s2 * KPAD1 + lane]);
            float x3v = bf2f(x0b[(size_t)s3 * KPAD1 + lane]);
            acc += e0 * x0v + e1 * x1v + e2 * x2v + e3 * x3v;
        }
        for (; j < nv; ++j) {
            f32x4 e = *(const f32x4*)&se[j * 4];
            acc += e * bf2f(x0b[(size_t)ssrc[j] * KPAD1 + lane]);
        }
        __syncthreads();
    }
    DEN_REDUCE
    #pragma unroll
    for (int h = 0; h < HEADS; ++h)
        aggx[(size_t)d * HC1 + h * 64 + lane] = f2bf(acc[h] * rd[h]);
}

// ---------------------------------------------------------------- agg layer 2 (gather h2; resid+ReLU; fused layer-3 logits)
__global__ __launch_bounds__(64)
void agg2_kernel(const ushort_t* __restrict__ comb,
                 const float* __restrict__ als, const float* __restrict__ ald,
                 const int* __restrict__ row_ptr, const int* __restrict__ csr_src,
                 const float* __restrict__ w_as3, const float* __restrict__ w_ad3,
                 ushort_t* __restrict__ xnext,
                 float* __restrict__ als3, float* __restrict__ ald3) {
    __shared__ int   ssrc[64];
    __shared__ float se[64 * 4];
    int d = blockIdx.x, lane = threadIdx.x;
    int hh = lane >> 4;                       // head of cols [lane*4, lane*4+4)
    MAX_PASS(als, ald)
    float den[HEADS] = {};
    f32x4 acc = (f32x4)0.f;                   // 4 cols (pk_fma)
    for (int base = beg; base < end; base += 64) {
        E_CHUNK(als)
        int j = 0;
        for (; j + 8 <= nv; j += 8) {
            int s0 = ssrc[j],     s1 = ssrc[j + 1], s2 = ssrc[j + 2], s3 = ssrc[j + 3];
            int s4 = ssrc[j + 4], s5 = ssrc[j + 5], s6 = ssrc[j + 6], s7 = ssrc[j + 7];
            float e0 = se[j * 4 + hh],       e1 = se[(j + 1) * 4 + hh];
            float e2 = se[(j + 2) * 4 + hh], e3 = se[(j + 3) * 4 + hh];
            float e4 = se[(j + 4) * 4 + hh], e5 = se[(j + 5) * 4 + hh];
            float e6 = se[(j + 6) * 4 + hh], e7 = se[(j + 7) * 4 + hh];
            f32x4 x0 = bf4_to_f32x4(*(const ushort4_t*)&comb[(size_t)s0 * N2S + lane * 4]);
            f32x4 x1 = bf4_to_f32x4(*(const ushort4_t*)&comb[(size_t)s1 * N2S + lane * 4]);
            f32x4 x2 = bf4_to_f32x4(*(const ushort4_t*)&comb[(size_t)s2 * N2S + lane * 4]);
            f32x4 x3 = bf4_to_f32x4(*(const ushort4_t*)&comb[(size_t)s3 * N2S + lane * 4]);
            f32x4 x4 = bf4_to_f32x4(*(const ushort4_t*)&comb[(size_t)s4 * N2S + lane * 4]);
            f32x4 x5 = bf4_to_f32x4(*(const ushort4_t*)&comb[(size_t)s5 * N2S + lane * 4]);
            f32x4 x6 = bf4_to_f32x4(*(const ushort4_t*)&comb[(size_t)s6 * N2S + lane * 4]);
            f32x4 x7 = bf4_to_f32x4(*(const ushort4_t*)&comb[(size_t)s7 * N2S + lane * 4]);
            acc += e0 * x0 + e1 * x1 + e2 * x2 + e3 * x3
                 + e4 * x4 + e5 * x5 + e6 * x6 + e7 * x7;
        }
        for (; j < nv; ++j) {
            float e = se[j * 4 + hh];
            f32x4 xv = bf4_to_f32x4(*(const ushort4_t*)&comb[(size_t)ssrc[j] * N2S + lane * 4]);
            acc += e * xv;
        }
        __syncthreads();
    }
    DEN_REDUCE
    float r = rd[hh];
    f32x4 rv = bf4_to_f32x4(*(const ushort4_t*)&comb[(size_t)d * N2S + 256 + lane * 4]);
    float v0 = fmaxf(acc.x * r + rv.x, 0.f);
    float v1 = fmaxf(acc.y * r + rv.y, 0.f);
    float v2 = fmaxf(acc.z * r + rv.z, 0.f);
    float v3 = fmaxf(acc.w * r + rv.w, 0.f);
    ushort4_t o;
    o.x = f2bf(v0); o.y = f2bf(v1); o.z = f2bf(v2); o.w = f2bf(v3);
    *(ushort4_t*)&xnext[(size_t)d * HC1 + lane * 4] = o;
    // fused layer-3 logits
    f32x4 ps = (f32x4)0.f, pd = (f32x4)0.f;
    float v[4] = {v0, v1, v2, v3};
    #pragma unroll
    for (int j = 0; j < 4; ++j) {
        f32x4 wsj = *(const f32x4*)&w_as3[(lane * 4 + j) * 4];
        f32x4 wdj = *(const f32x4*)&w_ad3[(lane * 4 + j) * 4];
        ps += v[j] * wsj;
        pd += v[j] * wdj;
    }
    #pragma unroll
    for (int off = 32; off; off >>= 1) {
        #pragma unroll
        for (int h = 0; h < HEADS; ++h) {
            ps[h] += __shfl_xor(ps[h], off);
            pd[h] += __shfl_xor(pd[h], off);
        }
    }
    if (lane == 0) {
        *(f32x4*)&als3[d * 4] = ps;
        *(f32x4*)&ald3[d * 4] = pd;
    }
}

// ---------------------------------------------------------------- agg layer 3 (gather x2 256 cols -> aggx3[N,1024])
__global__ __launch_bounds__(64)
void agg3_kernel(const ushort_t* __restrict__ x2b,
                 const float* __restrict__ als, const float* __restrict__ ald,
                 const int* __restrict__ row_ptr, const int* __restrict__ csr_src,
                 ushort_t* __restrict__ aggx) {
    __shared__ int   ssrc[64];
    __shared__ float se[64 * 4];
    int d = blockIdx.x, lane = threadIdx.x;
    MAX_PASS(als, ald)
    float den[HEADS] = {};
    f32x4 acc[HEADS] = {};                    // acc[h] = 4 cols (pk_fma)
    for (int base = beg; base < end; base += 64) {
        E_CHUNK(als)
        int j = 0;
        for (; j + 4 <= nv; j += 4) {
            int s0 = ssrc[j], s1 = ssrc[j + 1], s2 = ssrc[j + 2], s3 = ssrc[j + 3];
            f32x4 e0 = *(const f32x4*)&se[j * 4];
            f32x4 e1 = *(const f32x4*)&se[(j + 1) * 4];
            f32x4 e2 = *(const f32x4*)&se[(j + 2) * 4];
            f32x4 e3 = *(const f32x4*)&se[(j + 3) * 4];
            f32x4 x0 = bf4_to_f32x4(*(const ushort4_t*)&x2b[(size_t)s0 * HC1 + lane * 4]);
            f32x4 x1 = bf4_to_f32x4(*(const ushort4_t*)&x2b[(size_t)s1 * HC1 + lane * 4]);
            f32x4 x2 = bf4_to_f32x4(*(const ushort4_t*)&x2b[(size_t)s2 * HC1 + lane * 4]);
            f32x4 x3 = bf4_to_f32x4(*(const ushort4_t*)&x2b[(size_t)s3 * HC1 + lane * 4]);
            #pragma unroll
            for (int h = 0; h < HEADS; ++h)
                acc[h] += e0[h] * x0 + e1[h] * x1 + e2[h] * x2 + e3[h] * x3;
        }
        for (; j < nv; ++j) {
            f32x4 e = *(const f32x4*)&se[j * 4];
            f32x4 xv = bf4_to_f32x4(*(const ushort4_t*)&x2b[(size_t)ssrc[j] * HC1 + lane * 4]);
            #pragma unroll
            for (int h = 0; h < HEADS; ++h) acc[h] += e[h] * xv;
        }
        __syncthreads();
    }
    DEN_REDUCE
    #pragma unroll
    for (int h = 0; h < HEADS; ++h) {
        ushort4_t o;
        o.x = f2bf(acc[h].x * rd[h]); o.y = f2bf(acc[h].y * rd[h]);
        o.z = f2bf(acc[h].z * rd[h]); o.w = f2bf(acc[h].w * rd[h]);
        *(ushort4_t*)&aggx[(size_t)d * 1024 + h * HC1 + lane * 4] = o;
    }
}

// ---------------------------------------------------------------- launch
extern "C" void kernel_launch(void* const* d_in, const int* in_sizes, int n_in,
                              void* d_out, int out_size, void* d_ws, size_t ws_size,
                              hipStream_t stream) {
    const float* x0   = (const float*)d_in[0];
    const int*   ei   = (const int*)d_in[1];
    const float* W1   = (const float*)d_in[2];
    const float* as1  = (const float*)d_in[3];
    const float* ad1  = (const float*)d_in[4];
    const float* res1 = (const float*)d_in[5];
    const float* b1   = (const float*)d_in[6];
    const float* W2   = (const float*)d_in[7];
    const float* as2  = (const float*)d_in[8];
    const float* ad2  = (const float*)d_in[9];
    const float* res2 = (const float*)d_in[10];
    const float* b2   = (const float*)d_in[11];
    const float* W3   = (const float*)d_in[12];
    const float* as3  = (const float*)d_in[13];
    const float* ad3  = (const float*)d_in[14];
    const float* res3 = (const float*)d_in[15];
    const float* b3   = (const float*)d_in[16];

    char* p = (char*)d_ws;
    auto alloc = [&](size_t bytes) -> void* {
        void* r = (void*)p;
        p += (bytes + 255) & ~(size_t)255;
        return r;
    };
    int*      cnt     = (int*)alloc((size_t)NNODES * 4);
    int*      incl    = (int*)alloc((size_t)NNODES * 4);
    int*      bsums   = (int*)alloc((size_t)SCB * 4);
    int*      row_ptr = (int*)alloc((size_t)(NNODES + 1) * 4);
    int*      cursor  = (int*)alloc((size_t)NNODES * 4);
    int*      csr_src = (int*)alloc((size_t)NTOT * 4);
    float*    als     = (float*)alloc((size_t)NNODES * HEADS * 4);
    float*    ald     = (float*)alloc((size_t)NNODES * HEADS * 4);
    float*    als3    = (float*)alloc((size_t)NNODES * HEADS * 4);
    float*    ald3    = (float*)alloc((size_t)NNODES * HEADS * 4);
    ushort_t* x0b     = (ushort_t*)alloc((size_t)NNODES * KPAD1 * 2);
    ushort_t* x2      = (ushort_t*)alloc((size_t)NNODES * HC1 * 2);
    ushort_t* Bt1     = (ushort_t*)alloc((size_t)HC1 * K1S * 2);
    ushort_t* Bt2     = (ushort_t*)alloc((size_t)N2S * HC1 * 2);
    float*    bias512 = (float*)alloc((size_t)N2S * 4);
    ushort_t* Bt3     = (ushort_t*)alloc((size_t)NC * K3S * 2);
    float*    w_as1   = (float*)alloc((size_t)KPAD1 * 4 * 4);
    float*    w_ad1   = (float*)alloc((size_t)KPAD1 * 4 * 4);
    float*    w_as2   = (float*)alloc((size_t)HC1 * 4 * 4);
    float*    w_ad2   = (float*)alloc((size_t)HC1 * 4 * 4);
    float*    w_as3   = (float*)alloc((size_t)HC1 * 4 * 4);
    float*    w_ad3   = (float*)alloc((size_t)HC1 * 4 * 4);
    // aliased region: layer-1/2 temporaries, reused as aggx3 [N,1024] bf16 (102.4 MB)
    char*     big     = (char*)alloc((size_t)NNODES * 1024 * 2);
    ushort_t* aggx1   = (ushort_t*)big;                                  // [N,256]
    ushort_t* x1      = (ushort_t*)(big + (size_t)NNODES * HC1 * 2);     // [N,256]
    ushort_t* comb    = (ushort_t*)(big + (size_t)NNODES * HC1 * 4);     // [N,512]
    ushort_t* aggx3   = (ushort_t*)big;                                  // [N,1024] (layer 3)

    hipMemsetAsync(cnt, 0, (size_t)NNODES * 4, stream);

    int tb = 256;
    int nscan = (NNODES + SCB - 1) / SCB;
    count_kernel<<<(NTOT + tb - 1) / tb, tb, 0, stream>>>(ei, cnt);
    scan1_kernel<<<nscan, SCB, 0, stream>>>(cnt, incl, bsums, NNODES);
    scan2_kernel<<<1, SCB, 0, stream>>>(bsums, nscan);
    scan3_kernel<<<nscan, SCB, 0, stream>>>(cnt, incl, bsums, row_ptr, cursor, NNODES);
    scatter_kernel<<<(NTOT + tb - 1) / tb, tb, 0, stream>>>(ei, cursor, csr_src);

    prep_kernel<<<(PREP_TOTAL + 255) / 256, 256, 0, stream>>>(
        x0, W1, res1, W2, res2, W3, res3, as1, ad1, as2, ad2, as3, ad3, b2,
        x0b, Bt1, Bt2, Bt3, bias512, w_as1, w_ad1, w_as2, w_ad2, w_as3, w_ad3);

    auto gemm = [&](const ushort_t* A1, int lda1, const ushort_t* A2, int lda2, int Ksplit,
                    const ushort_t* Bt, const float* bias,
                    float* Cf, ushort_t* Cb, int M, int Nn, int K, int relu) {
        dim3 g((Nn + BN - 1) / BN, (M + BM - 1) / BM);
        gemm_mfma_kernel<<<g, 256, 0, stream>>>(A1, lda1, A2, lda2, Ksplit, Bt, bias,
                                                Cf, Cb, M, Nn, K, relu);
    };

    // ---- layer 1 (aggregate-then-transform; GEMM reads [aggx1 | x0b])
    logits_gemv_kernel<<<NNODES, 64, 0, stream>>>(x0b, KPAD1, w_as1, w_ad1, als, ald);
    agg1_kernel<<<NNODES, 64, 0, stream>>>(x0b, als, ald, row_ptr, csr_src, aggx1);
    gemm(aggx1, HC1, x0b, KPAD1, HC1, Bt1, b1, nullptr, x1, NNODES, HC1, K1S, 1);

    // ---- layer 2 (stacked GEMM [h2|resid]; agg2 also emits layer-3 logits)
    gemm(x1, HC1, x1, HC1, HC1, Bt2, bias512, nullptr, comb, NNODES, N2S, HC1, 0);
    logits_gemv_kernel<<<NNODES, 64, 0, stream>>>(x1, HC1, w_as2, w_ad2, als, ald);
    agg2_kernel<<<NNODES, 64, 0, stream>>>(comb, als, ald, row_ptr, csr_src,
                                           w_as3, w_ad3, x2, als3, ald3);

    // ---- layer 3 (aggregate-then-transform; GEMM reads [aggx3 | x2])
    agg3_kernel<<<NNODES, 64, 0, stream>>>(x2, als3, ald3, row_ptr, csr_src, aggx3);
    gemm(aggx3, 1024, x2, HC1, 1024, Bt3, b3, (float*)d_out, nullptr, NNODES, NC, K3S, 0);
}